// Round 5
// baseline (322.339 us; speedup 1.0000x reference)
//
#include <hip/hip_runtime.h>
#include <math.h>

// Problem constants (B,L,H,D) = (2,4096,8,64); sample_k = n_top = 45
#define B_ 2
#define L_ 4096
#define H_ 8
#define D_ 64
#define S_ 45
#define NTOP_ 45
#define SCALE 0.125f  // 1/sqrt(64)
#define TKEYS 64      // keys per attn block
#define NSPLIT 64     // key splits per (b,h)

// DPP helper: move with compile-time ctrl (quad_perm patterns, butterfly-safe).
template<int CTRL>
__device__ __forceinline__ float dpp_permf(float x) {
    return __int_as_float(__builtin_amdgcn_update_dpp(
        0, __float_as_int(x), CTRL, 0xF, 0xF, true));
}

// ---------------- K1: sparsity measure M = max_s(q.k_s) - sum_s/L ----------------
// At the L2 random-gather LINE-RATE ceiling — confirmed across 6 layouts (r1:
// head-pair contiguity halved segment count, duration flat 42us). Binding resource
// is 64B lines/cyc. DO NOT add work or change layout here.
__global__ __launch_bounds__(256) void compute_M_kernel(
    const float* __restrict__ q, const float* __restrict__ k,
    const int* __restrict__ samp, float* __restrict__ M) {
    __shared__ int sIdx[8 * 48];    // 8 queries x 45 idx + 3 pad
    int tid = threadIdx.x;
    int g   = blockIdx.x;           // 0..4095
    int xcd = g & 7;                // slice id: b = xcd>>2, head-pair = xcd&3
    int chunk = g >> 3;             // 0..511 -> 8 queries each
    int b  = xcd >> 2;
    int h0 = (xcd & 3) * 2;
    int l0 = chunk * 8;

    for (int i = tid; i < 8 * S_; i += 256) {
        int qq = i / S_, ss = i - qq * S_;
        sIdx[qq * 48 + ss] = samp[(long)(l0 + qq) * S_ + ss];
    }
    if (tid < 24) sIdx[(tid / 3) * 48 + S_ + (tid % 3)] = 0;  // pad slots 45..47
    __syncthreads();

    int lane = tid & 63, wave = tid >> 6;
    int c  = lane & 31;             // float4 slot within 512B row-pair
    int q8 = wave * 2 + (lane >> 5);
    int l  = l0 + q8;

    float4 q4 = ((const float4*)(q + (((long)(b * L_ + l)) * H_ + h0) * D_))[c];
    const float4* kb4 = (const float4*)(k + ((long)b * L_ * H_ + h0) * (long)D_);
    const int* myIdx = sIdx + q8 * 48;

    float4 f0 = kb4[(long)myIdx[0] * 128 + c];
    float4 f1 = kb4[(long)myIdx[1] * 128 + c];
    float4 f2 = kb4[(long)myIdx[2] * 128 + c];

    float vmax = -INFINITY, vsum = 0.f;
    #pragma unroll 3
    for (int s = 0; s < S_; ++s) {
        float4 nf = kb4[(long)myIdx[s + 3] * 128 + c];
        float p = q4.x * f0.x + q4.y * f0.y + q4.z * f0.z + q4.w * f0.w;
        p += dpp_permf<0xB1>(p);        // quad_perm xor 1 (VALU pipe)
        p += dpp_permf<0x4E>(p);        // quad_perm xor 2 (VALU pipe)
        p += __shfl_xor(p, 4, 64);
        p += __shfl_xor(p, 8, 64);
        vmax = fmaxf(vmax, p);
        vsum += p;
        f0 = f1; f1 = f2; f2 = nf;
    }
    if ((lane & 15) == 0) {
        int h = h0 + ((lane >> 4) & 1);
        M[(long)(b * 8 + h) * L_ + l] = vmax - vsum * (1.0f / (float)L_);
    }
}

// ---------------- K2: top-45 set per (b,h) via byte-radix select (r0-proven) ----------------
// 16 blocks, measured cheap (r1->r2 ledger). Output order arbitrary (reference
// scatters row u to M_top[u]); ties -> lowest index. Also zeroes K3's per-bh
// completion counters (stream-ordered before K3 each iteration).
__global__ __launch_bounds__(256) void topk_kernel(
    const float* __restrict__ M, int* __restrict__ topIdx, int* __restrict__ cnt) {
    __shared__ unsigned int hist[256];
    __shared__ unsigned int suf[257];
    __shared__ unsigned int wsum[4];
    __shared__ int sBin, sRemain, sCnt, sTieCnt;
    __shared__ int tie[64];

    int bh = blockIdx.x, tid = threadIdx.x;
    int lane = tid & 63, wave = tid >> 6;
    const float* row = M + (long)bh * L_;

    if (tid == 0) cnt[bh] = 0;   // reset K3 tail counter for this iteration

    unsigned int key[16];
    #pragma unroll
    for (int j = 0; j < 16; ++j) {
        unsigned int bts = __float_as_uint(row[tid + 256 * j]);
        key[j] = bts ^ ((unsigned int)((int)bts >> 31) | 0x80000000u);
    }

    unsigned int prefix = 0, pmask = 0;
    int remain = NTOP_;
    #pragma unroll 1
    for (int pass = 3; pass >= 0; --pass) {
        int shift = pass * 8;
        hist[tid] = 0;
        __syncthreads();
        #pragma unroll
        for (int j = 0; j < 16; ++j) {
            if ((key[j] & pmask) == prefix)
                atomicAdd(&hist[(key[j] >> shift) & 255u], 1u);
        }
        __syncthreads();
        unsigned int s = hist[tid];
        #pragma unroll
        for (int off = 1; off < 64; off <<= 1) {
            unsigned int o = __shfl_down(s, off, 64);
            if (lane + off < 64) s += o;
        }
        if (lane == 0) wsum[wave] = s;
        __syncthreads();
        unsigned int add = 0;
        for (int w = wave + 1; w < 4; ++w) add += wsum[w];
        s += add;
        suf[tid] = s;
        if (tid == 0) suf[256] = 0;
        __syncthreads();
        if (suf[tid] >= (unsigned int)remain && suf[tid + 1] < (unsigned int)remain) {
            sBin = tid;
            sRemain = remain - (int)suf[tid + 1];
        }
        __syncthreads();
        prefix |= ((unsigned int)sBin) << shift;
        pmask  |= 0xFFu << shift;
        remain  = sRemain;
        __syncthreads();
    }

    if (tid == 0) { sCnt = 0; sTieCnt = 0; }
    __syncthreads();
    int* outRow = topIdx + bh * NTOP_;
    #pragma unroll
    for (int j = 0; j < 16; ++j) {
        int idx = tid + 256 * j;
        if (key[j] > prefix) {
            int pos = atomicAdd(&sCnt, 1);
            outRow[pos] = idx;
        } else if (key[j] == prefix) {
            int tp = atomicAdd(&sTieCnt, 1);
            if (tp < 64) tie[tp] = idx;
        }
    }
    __syncthreads();
    if (tid == 0) {
        int base = sCnt;
        int tc = sTieCnt < 64 ? sTieCnt : 64;
        for (int t = 0; t < remain; ++t) {
            int mi = 0x7fffffff, mj = 0;
            for (int j2 = 0; j2 < tc; ++j2)
                if (tie[j2] < mi) { mi = tie[j2]; mj = j2; }
            outRow[base + t] = mi;
            tie[mj] = 0x7fffffff;
        }
    }
}

// ---------------- K3: key-strip attention + zero + split-K tail reduce ----------------
// Changes vs r4 (both follow the proven cheap-fusion pattern):
// (1) LDS 61.4 -> 47.9 KB: S-phase results stay in registers; P is written into the
//     dead sQ buffer after a barrier -> 3 blocks/CU (launch_bounds(256,3)).
// (2) Zero region re-partitioned: block (bh,split) zeroes out rows (b, key0..key0+63, h, :)
//     — exactly the rows bh's scatter can touch (union over splits covers all of out).
//     This makes per-bh completion-counter ordering sufficient for the fused tail:
//     last block of bh's 64 splits reduces pOut/plPart across splits, normalizes,
//     scatters. reduce_norm dispatch eliminated.
#define STRIDE 68
__global__ __launch_bounds__(256, 3) void attn_strip_kernel(
    const float* __restrict__ q, const float* __restrict__ k,
    const float* __restrict__ v, const int* __restrict__ topIdx,
    float* __restrict__ pOut, float* __restrict__ plPart,
    float* __restrict__ out, int* __restrict__ cnt, int nsplit) {
    __shared__ float sQ[48 * STRIDE];     // 13.1 KB (aliased as P after S phase)
    __shared__ float sK[TKEYS * STRIDE];  // 17.4 KB
    __shared__ float sV[TKEYS * STRIDE];  // 17.4 KB
    __shared__ float lsumS[NTOP_];
    __shared__ int isLastS;

    int g = blockIdx.x;
    int xcd = g & 7;
    int s0 = g >> 3;
    int grp = s0 / nsplit;
    int bh = xcd + 8 * grp;
    int split = s0 - grp * nsplit;
    int b = bh >> 3, h = bh & 7;
    int tid = threadIdx.x;
    int key0 = split * TKEYS;

    // ---- issue ALL global loads up front ----
    #pragma unroll
    for (int j = 0; j < 3; ++j) {
        int i = tid + 256 * j;
        int u = i >> 4, d4 = i & 15;
        float4 val = make_float4(0.f, 0.f, 0.f, 0.f);
        if (u < NTOP_) {
            int lq = topIdx[bh * NTOP_ + u];
            val = *(const float4*)(q + (((long)(b * L_ + lq)) * H_ + h) * D_ + 4 * d4);
        }
        *(float4*)(sQ + u * STRIDE + 4 * d4) = val;
    }
    #pragma unroll
    for (int j = 0; j < 4; ++j) {
        int i = tid + 256 * j;
        int r = i >> 4, d4 = i & 15;
        long off = (((long)(b * L_ + key0 + r)) * H_ + h) * D_ + 4 * d4;
        *(float4*)(sK + r * STRIDE + 4 * d4) = *(const float4*)(k + off);
        *(float4*)(sV + r * STRIDE + 4 * d4) = *(const float4*)(v + off);
    }

    // fused zero: rows (b, key0+r, h, :) for r in [0,64) — the rows this bh scatters to.
    // (L_/nsplit == TKEYS rows per block at nsplit=64; generic for smaller nsplit.)
    {
        int rows = L_ / nsplit;                    // rows per block
        int row0 = split * rows;
        float4 z = make_float4(0.f, 0.f, 0.f, 0.f);
        for (int idx = tid; idx < rows * 16; idx += 256) {
            int r = idx >> 4, c4 = idx & 15;       // 16 float4 per 256B row
            *((float4*)(out + (((long)(b * L_ + row0 + r)) * H_ + h) * D_) + c4) = z;
        }
    }
    __syncthreads();

    // ---- S phase: thread (ty,tx): u = 3ty+i (i<3) x keys tx+16j (j<4) -> registers ----
    int tx = tid & 15, ty = tid >> 4;
    float acc[3][4];
    #pragma unroll
    for (int i = 0; i < 3; ++i)
        #pragma unroll
        for (int j = 0; j < 4; ++j) acc[i][j] = 0.f;

    #pragma unroll 4
    for (int d4 = 0; d4 < 16; ++d4) {
        float4 qv[3];
        #pragma unroll
        for (int i = 0; i < 3; ++i)
            qv[i] = *(const float4*)(sQ + (3 * ty + i) * STRIDE + 4 * d4);
        #pragma unroll
        for (int j = 0; j < 4; ++j) {
            float4 kv = *(const float4*)(sK + (tx + 16 * j) * STRIDE + 4 * d4);
            #pragma unroll
            for (int i = 0; i < 3; ++i)
                acc[i][j] += qv[i].x * kv.x + qv[i].y * kv.y + qv[i].z * kv.z + qv[i].w * kv.w;
        }
    }
    __syncthreads();   // all sQ reads complete before overwrite

    float* sP = sQ;    // alias: P reuses the dead Q buffer (same 48 x STRIDE shape)
    #pragma unroll
    for (int i = 0; i < 3; ++i) {
        #pragma unroll
        for (int j = 0; j < 4; ++j)
            sP[(3 * ty + i) * STRIDE + tx + 16 * j] = __expf(acc[i][j] * SCALE);
    }
    __syncthreads();

    // ---- PV phase: thread (uy,dx): u = 3uy+i (i<3) x d = 4dx..4dx+3 ----
    int dx = tid & 15, uy = tid >> 4;
    float o[3][4];
    float ls[3];
    #pragma unroll
    for (int i = 0; i < 3; ++i) {
        ls[i] = 0.f;
        #pragma unroll
        for (int c = 0; c < 4; ++c) o[i][c] = 0.f;
    }
    #pragma unroll 4
    for (int k4 = 0; k4 < 16; ++k4) {
        float pa[3][4];
        #pragma unroll
        for (int i = 0; i < 3; ++i)
            *(float4*)pa[i] = *(const float4*)(sP + (3 * uy + i) * STRIDE + 4 * k4);
        #pragma unroll
        for (int c = 0; c < 4; ++c) {
            float4 vr = *(const float4*)(sV + (4 * k4 + c) * STRIDE + 4 * dx);
            #pragma unroll
            for (int i = 0; i < 3; ++i) {
                o[i][0] += pa[i][c] * vr.x;
                o[i][1] += pa[i][c] * vr.y;
                o[i][2] += pa[i][c] * vr.z;
                o[i][3] += pa[i][c] * vr.w;
                ls[i]   += pa[i][c];
            }
        }
    }
    #pragma unroll
    for (int i = 0; i < 3; ++i) {
        int u = 3 * uy + i;
        if (u < NTOP_) {
            long base = ((long)(split * 16 + bh) * NTOP_ + u) * D_;
            *(float4*)(pOut + base + 4 * dx) = make_float4(o[i][0], o[i][1], o[i][2], o[i][3]);
            if (dx == 0) plPart[(long)(split * 16 + bh) * NTOP_ + u] = ls[i];
        }
    }

    // ---- split-K tail: last block of this bh reduces + normalizes + scatters ----
    __threadfence();                       // make pOut/plPart/zeros device-visible
    if (tid == 0) {
        int old = atomicAdd(&cnt[bh], 1);  // device-scope
        isLastS = (old == nsplit - 1) ? 1 : 0;
    }
    __syncthreads();
    if (isLastS) {
        for (int u = tid; u < NTOP_; u += 256) {
            float lt = 0.f;
            for (int s = 0; s < nsplit; ++s)
                lt += plPart[(long)(s * 16 + bh) * NTOP_ + u];
            lsumS[u] = lt;
        }
        __syncthreads();
        for (int idx = tid; idx < NTOP_ * D_; idx += 256) {
            int u = idx >> 6, d = idx & 63;
            float a = 0.f;
            const float* pb = pOut + ((long)bh * NTOP_ + u) * D_ + d;
            #pragma unroll 8
            for (int s = 0; s < nsplit; ++s) a += pb[(long)s * 16 * NTOP_ * D_];
            int lq = topIdx[bh * NTOP_ + u];
            out[(((long)(b * L_ + lq)) * H_ + h) * D_ + d] = a / lsumS[u];
        }
    }
}

extern "C" void kernel_launch(void* const* d_in, const int* in_sizes, int n_in,
                              void* d_out, int out_size, void* d_ws, size_t ws_size,
                              hipStream_t stream) {
    const float* q = (const float*)d_in[0];
    const float* k = (const float*)d_in[1];
    const float* v = (const float*)d_in[2];
    // d_in[3] = attn_mask (unused)
    const int* samp = (const int*)d_in[4];
    float* out = (float*)d_out;

    char* ws = (char*)d_ws;
    const size_t mBytes   = (size_t)B_ * H_ * L_ * sizeof(float);   // 512 KB
    const size_t topBytes = (size_t)B_ * H_ * NTOP_ * sizeof(int);  // 2880 B
    const size_t plBytes  = (size_t)NSPLIT * 16 * NTOP_ * sizeof(float);
    const size_t cntBytes = 256;                                    // 16 ints, padded
    float* M      = (float*)ws;
    int*   topIdx = (int*)(ws + mBytes);
    float* plPart = (float*)(ws + mBytes + topBytes);
    int*   cnt    = (int*)(ws + mBytes + topBytes + plBytes);
    float* pOut   = (float*)(ws + mBytes + topBytes + plBytes + cntBytes);

    int nsplit = NSPLIT;
    while (nsplit > 1) {
        size_t need = mBytes + topBytes + plBytes + cntBytes +
                      (size_t)nsplit * 16 * NTOP_ * D_ * sizeof(float);
        if (need <= ws_size) break;
        nsplit >>= 1;
    }

    compute_M_kernel<<<4096, 256, 0, stream>>>(q, k, samp, M);

    topk_kernel<<<B_ * H_, 256, 0, stream>>>(M, topIdx, cnt);

    attn_strip_kernel<<<nsplit * B_ * H_, 256, 0, stream>>>(
        q, k, v, topIdx, pOut, plPart, out, cnt, nsplit);
}

// Round 6
// 154.378 us; speedup vs baseline: 2.0880x; 2.0880x over previous
//
#include <hip/hip_runtime.h>
#include <math.h>

// Problem constants (B,L,H,D) = (2,4096,8,64); sample_k = n_top = 45
#define B_ 2
#define L_ 4096
#define H_ 8
#define D_ 64
#define S_ 45
#define NTOP_ 45
#define SCALE 0.125f  // 1/sqrt(64)
#define TKEYS 64      // keys per attn block
#define NSPLIT 64     // key splits per (b,h)

// DPP helper: move with compile-time ctrl (quad_perm patterns, butterfly-safe).
template<int CTRL>
__device__ __forceinline__ float dpp_permf(float x) {
    return __int_as_float(__builtin_amdgcn_update_dpp(
        0, __float_as_int(x), CTRL, 0xF, 0xF, true));
}

// ---------------- K1: sparsity measure M = max_s(q.k_s) - sum_s/L ----------------
// At the L2 random-gather LINE-RATE ceiling — confirmed across 6 layouts (r1:
// head-pair contiguity halved segment count, duration flat 42us). Binding resource
// is 64B lines/cyc. DO NOT add work or change layout here.
__global__ __launch_bounds__(256) void compute_M_kernel(
    const float* __restrict__ q, const float* __restrict__ k,
    const int* __restrict__ samp, float* __restrict__ M) {
    __shared__ int sIdx[8 * 48];    // 8 queries x 45 idx + 3 pad
    int tid = threadIdx.x;
    int g   = blockIdx.x;           // 0..4095
    int xcd = g & 7;                // slice id: b = xcd>>2, head-pair = xcd&3
    int chunk = g >> 3;             // 0..511 -> 8 queries each
    int b  = xcd >> 2;
    int h0 = (xcd & 3) * 2;
    int l0 = chunk * 8;

    for (int i = tid; i < 8 * S_; i += 256) {
        int qq = i / S_, ss = i - qq * S_;
        sIdx[qq * 48 + ss] = samp[(long)(l0 + qq) * S_ + ss];
    }
    if (tid < 24) sIdx[(tid / 3) * 48 + S_ + (tid % 3)] = 0;  // pad slots 45..47
    __syncthreads();

    int lane = tid & 63, wave = tid >> 6;
    int c  = lane & 31;             // float4 slot within 512B row-pair
    int q8 = wave * 2 + (lane >> 5);
    int l  = l0 + q8;

    float4 q4 = ((const float4*)(q + (((long)(b * L_ + l)) * H_ + h0) * D_))[c];
    const float4* kb4 = (const float4*)(k + ((long)b * L_ * H_ + h0) * (long)D_);
    const int* myIdx = sIdx + q8 * 48;

    float4 f0 = kb4[(long)myIdx[0] * 128 + c];
    float4 f1 = kb4[(long)myIdx[1] * 128 + c];
    float4 f2 = kb4[(long)myIdx[2] * 128 + c];

    float vmax = -INFINITY, vsum = 0.f;
    #pragma unroll 3
    for (int s = 0; s < S_; ++s) {
        float4 nf = kb4[(long)myIdx[s + 3] * 128 + c];
        float p = q4.x * f0.x + q4.y * f0.y + q4.z * f0.z + q4.w * f0.w;
        p += dpp_permf<0xB1>(p);        // quad_perm xor 1 (VALU pipe)
        p += dpp_permf<0x4E>(p);        // quad_perm xor 2 (VALU pipe)
        p += __shfl_xor(p, 4, 64);
        p += __shfl_xor(p, 8, 64);
        vmax = fmaxf(vmax, p);
        vsum += p;
        f0 = f1; f1 = f2; f2 = nf;
    }
    if ((lane & 15) == 0) {
        int h = h0 + ((lane >> 4) & 1);
        M[(long)(b * 8 + h) * L_ + l] = vmax - vsum * (1.0f / (float)L_);
    }
}

// ---------------- K2: top-45 set per (b,h) via byte-radix select (r0-proven) ----------------
// 16 blocks, measured cheap (r1->r2 ledger). Output order arbitrary (reference
// scatters row u to M_top[u]); ties -> lowest index.
__global__ __launch_bounds__(256) void topk_kernel(
    const float* __restrict__ M, int* __restrict__ topIdx) {
    __shared__ unsigned int hist[256];
    __shared__ unsigned int suf[257];
    __shared__ unsigned int wsum[4];
    __shared__ int sBin, sRemain, sCnt, sTieCnt;
    __shared__ int tie[64];

    int bh = blockIdx.x, tid = threadIdx.x;
    int lane = tid & 63, wave = tid >> 6;
    const float* row = M + (long)bh * L_;

    unsigned int key[16];
    #pragma unroll
    for (int j = 0; j < 16; ++j) {
        unsigned int bts = __float_as_uint(row[tid + 256 * j]);
        key[j] = bts ^ ((unsigned int)((int)bts >> 31) | 0x80000000u);
    }

    unsigned int prefix = 0, pmask = 0;
    int remain = NTOP_;
    #pragma unroll 1
    for (int pass = 3; pass >= 0; --pass) {
        int shift = pass * 8;
        hist[tid] = 0;
        __syncthreads();
        #pragma unroll
        for (int j = 0; j < 16; ++j) {
            if ((key[j] & pmask) == prefix)
                atomicAdd(&hist[(key[j] >> shift) & 255u], 1u);
        }
        __syncthreads();
        unsigned int s = hist[tid];
        #pragma unroll
        for (int off = 1; off < 64; off <<= 1) {
            unsigned int o = __shfl_down(s, off, 64);
            if (lane + off < 64) s += o;
        }
        if (lane == 0) wsum[wave] = s;
        __syncthreads();
        unsigned int add = 0;
        for (int w = wave + 1; w < 4; ++w) add += wsum[w];
        s += add;
        suf[tid] = s;
        if (tid == 0) suf[256] = 0;
        __syncthreads();
        if (suf[tid] >= (unsigned int)remain && suf[tid + 1] < (unsigned int)remain) {
            sBin = tid;
            sRemain = remain - (int)suf[tid + 1];
        }
        __syncthreads();
        prefix |= ((unsigned int)sBin) << shift;
        pmask  |= 0xFFu << shift;
        remain  = sRemain;
        __syncthreads();
    }

    if (tid == 0) { sCnt = 0; sTieCnt = 0; }
    __syncthreads();
    int* outRow = topIdx + bh * NTOP_;
    #pragma unroll
    for (int j = 0; j < 16; ++j) {
        int idx = tid + 256 * j;
        if (key[j] > prefix) {
            int pos = atomicAdd(&sCnt, 1);
            outRow[pos] = idx;
        } else if (key[j] == prefix) {
            int tp = atomicAdd(&sTieCnt, 1);
            if (tp < 64) tie[tp] = idx;
        }
    }
    __syncthreads();
    if (tid == 0) {
        int base = sCnt;
        int tc = sTieCnt < 64 ? sTieCnt : 64;
        for (int t = 0; t < remain; ++t) {
            int mi = 0x7fffffff, mj = 0;
            for (int j2 = 0; j2 < tc; ++j2)
                if (tie[j2] < mi) { mi = tie[j2]; mj = j2; }
            outRow[base + t] = mi;
            tie[mj] = 0x7fffffff;
        }
    }
}

// ---------------- K3: key-strip attention (r4 form) + LDS shrink via P<-Q aliasing ----------------
// r4-proven: contiguous per-block zero fusion, all loads up front, pOut partials.
// NEW (validated orthogonally in r5's counters: LDS_Block 48128, VGPR 84, compiles
// clean): S-phase accumulates in registers, P overwrites the dead sQ buffer after a
// barrier. LDS 61.4 -> 47.9 KB -> 3 blocks/CU (launch_bounds(256,3)).
// NO threadfence / completion counter here — r5 proved device-scope fences in a
// 1024-block kernel cost ~180us (per-block L2 writeback on non-coherent XCD L2s).
#define STRIDE 68
__global__ __launch_bounds__(256, 3) void attn_strip_kernel(
    const float* __restrict__ q, const float* __restrict__ k,
    const float* __restrict__ v, const int* __restrict__ topIdx,
    float* __restrict__ pOut, float* __restrict__ plPart,
    float* __restrict__ out, int nsplit) {
    __shared__ float sQ[48 * STRIDE];     // 13.1 KB (aliased as P after S phase)
    __shared__ float sK[TKEYS * STRIDE];  // 17.4 KB
    __shared__ float sV[TKEYS * STRIDE];  // 17.4 KB

    int g = blockIdx.x;
    int xcd = g & 7;
    int s0 = g >> 3;
    int grp = s0 / nsplit;
    int bh = xcd + 8 * grp;
    int split = s0 - grp * nsplit;
    int b = bh >> 3, h = bh & 7;
    int tid = threadIdx.x;
    int key0 = split * TKEYS;

    // ---- issue ALL global loads up front (r0/r4 pattern) ----
    #pragma unroll
    for (int j = 0; j < 3; ++j) {
        int i = tid + 256 * j;
        int u = i >> 4, d4 = i & 15;
        float4 val = make_float4(0.f, 0.f, 0.f, 0.f);
        if (u < NTOP_) {
            int lq = topIdx[bh * NTOP_ + u];
            val = *(const float4*)(q + (((long)(b * L_ + lq)) * H_ + h) * D_ + 4 * d4);
        }
        *(float4*)(sQ + u * STRIDE + 4 * d4) = val;
    }
    #pragma unroll
    for (int j = 0; j < 4; ++j) {
        int i = tid + 256 * j;
        int r = i >> 4, d4 = i & 15;
        long off = (((long)(b * L_ + key0 + r)) * H_ + h) * D_ + 4 * d4;
        *(float4*)(sK + r * STRIDE + 4 * d4) = *(const float4*)(k + off);
        *(float4*)(sV + r * STRIDE + 4 * d4) = *(const float4*)(v + off);
    }

    // fused zero of this block's contiguous out slice (r4-proven: ~2.6us hidden)
    {
        long total4 = (long)B_ * L_ * H_ * D_ / 4;       // 1,048,576 float4
        long per = total4 / ((long)nsplit * 16);         // 1024 at nsplit=64
        float4* ob = (float4*)out + (long)g * per;
        float4 z = make_float4(0.f, 0.f, 0.f, 0.f);
        for (long j = tid; j < per; j += 256) ob[j] = z;
    }
    __syncthreads();

    // ---- S phase: thread (ty,tx): u = 3ty+i (i<3) x keys tx+16j (j<4) -> registers ----
    int tx = tid & 15, ty = tid >> 4;
    float acc[3][4];
    #pragma unroll
    for (int i = 0; i < 3; ++i)
        #pragma unroll
        for (int j = 0; j < 4; ++j) acc[i][j] = 0.f;

    #pragma unroll 4
    for (int d4 = 0; d4 < 16; ++d4) {
        float4 qv[3];
        #pragma unroll
        for (int i = 0; i < 3; ++i)
            qv[i] = *(const float4*)(sQ + (3 * ty + i) * STRIDE + 4 * d4);
        #pragma unroll
        for (int j = 0; j < 4; ++j) {
            float4 kv = *(const float4*)(sK + (tx + 16 * j) * STRIDE + 4 * d4);
            #pragma unroll
            for (int i = 0; i < 3; ++i)
                acc[i][j] += qv[i].x * kv.x + qv[i].y * kv.y + qv[i].z * kv.z + qv[i].w * kv.w;
        }
    }
    __syncthreads();   // all sQ reads complete before overwrite

    float* sP = sQ;    // alias: P reuses the dead Q buffer (same 48 x STRIDE shape)
    #pragma unroll
    for (int i = 0; i < 3; ++i) {
        #pragma unroll
        for (int j = 0; j < 4; ++j)
            sP[(3 * ty + i) * STRIDE + tx + 16 * j] = __expf(acc[i][j] * SCALE);
    }
    __syncthreads();

    // ---- PV phase: thread (uy,dx): u = 3uy+i (i<3) x d = 4dx..4dx+3 ----
    int dx = tid & 15, uy = tid >> 4;
    float o[3][4];
    float ls[3];
    #pragma unroll
    for (int i = 0; i < 3; ++i) {
        ls[i] = 0.f;
        #pragma unroll
        for (int c = 0; c < 4; ++c) o[i][c] = 0.f;
    }
    #pragma unroll 4
    for (int k4 = 0; k4 < 16; ++k4) {
        float pa[3][4];
        #pragma unroll
        for (int i = 0; i < 3; ++i)
            *(float4*)pa[i] = *(const float4*)(sP + (3 * uy + i) * STRIDE + 4 * k4);
        #pragma unroll
        for (int c = 0; c < 4; ++c) {
            float4 vr = *(const float4*)(sV + (4 * k4 + c) * STRIDE + 4 * dx);
            #pragma unroll
            for (int i = 0; i < 3; ++i) {
                o[i][0] += pa[i][c] * vr.x;
                o[i][1] += pa[i][c] * vr.y;
                o[i][2] += pa[i][c] * vr.z;
                o[i][3] += pa[i][c] * vr.w;
                ls[i]   += pa[i][c];
            }
        }
    }
    #pragma unroll
    for (int i = 0; i < 3; ++i) {
        int u = 3 * uy + i;
        if (u < NTOP_) {
            long base = ((long)(split * 16 + bh) * NTOP_ + u) * D_;
            *(float4*)(pOut + base + 4 * dx) = make_float4(o[i][0], o[i][1], o[i][2], o[i][3]);
            if (dx == 0) plPart[(long)(split * 16 + bh) * NTOP_ + u] = ls[i];
        }
    }
}

// ---------------- K4: reduce partials across splits, normalize, scatter (r0/r4 form) ----------------
__global__ __launch_bounds__(256) void reduce_norm_kernel(
    const int* __restrict__ topIdx, const float* __restrict__ pOut,
    const float* __restrict__ plPart, float* __restrict__ out, int nsplit) {
    __shared__ float part[4][64];
    __shared__ float lpart[4];
    int u = blockIdx.x, bh = blockIdx.y;
    int b = bh >> 3, h = bh & 7;
    int tid = threadIdx.x;
    int d = tid & 63, sg = tid >> 6;
    float acc = 0.f, lsum = 0.f;
    for (int s = sg; s < nsplit; s += 4) {
        acc  += pOut[((long)(s * 16 + bh) * NTOP_ + u) * D_ + d];
        lsum += plPart[(long)(s * 16 + bh) * NTOP_ + u];
    }
    part[sg][d] = acc;
    if (d == 0) lpart[sg] = lsum;
    __syncthreads();
    if (sg == 0) {
        float a = part[0][d] + part[1][d] + part[2][d] + part[3][d];
        float lt = lpart[0] + lpart[1] + lpart[2] + lpart[3];
        int lq = topIdx[bh * NTOP_ + u];
        out[(((long)(b * L_ + lq)) * H_ + h) * D_ + d] = a / lt;
    }
}

extern "C" void kernel_launch(void* const* d_in, const int* in_sizes, int n_in,
                              void* d_out, int out_size, void* d_ws, size_t ws_size,
                              hipStream_t stream) {
    const float* q = (const float*)d_in[0];
    const float* k = (const float*)d_in[1];
    const float* v = (const float*)d_in[2];
    // d_in[3] = attn_mask (unused)
    const int* samp = (const int*)d_in[4];
    float* out = (float*)d_out;

    char* ws = (char*)d_ws;
    const size_t mBytes   = (size_t)B_ * H_ * L_ * sizeof(float);   // 512 KB
    const size_t topBytes = (size_t)B_ * H_ * NTOP_ * sizeof(int);  // 2880 B
    const size_t plBytes  = (size_t)NSPLIT * 16 * NTOP_ * sizeof(float);
    float* M      = (float*)ws;
    int*   topIdx = (int*)(ws + mBytes);
    float* plPart = (float*)(ws + mBytes + topBytes);
    float* pOut   = (float*)(ws + mBytes + topBytes + plBytes);

    int nsplit = NSPLIT;
    while (nsplit > 1) {
        size_t need = mBytes + topBytes + plBytes +
                      (size_t)nsplit * 16 * NTOP_ * D_ * sizeof(float);
        if (need <= ws_size) break;
        nsplit >>= 1;
    }

    compute_M_kernel<<<4096, 256, 0, stream>>>(q, k, samp, M);

    topk_kernel<<<B_ * H_, 256, 0, stream>>>(M, topIdx);

    attn_strip_kernel<<<nsplit * B_ * H_, 256, 0, stream>>>(
        q, k, v, topIdx, pOut, plPart, out, nsplit);

    dim3 gn(NTOP_, B_ * H_);
    reduce_norm_kernel<<<gn, 256, 0, stream>>>(topIdx, pOut, plPart, out, nsplit);
}